// Round 8
// baseline (742.203 us; speedup 1.0000x reference)
//
#include <hip/hip_runtime.h>
#include <hip/hip_bf16.h>

#define N_NODES 50000
#define N_EDGES 400000
#define IN_CH   814
#define HID     128
#define HEADS1  4
#define NUM_GRAPHS 64
#define NUM_CLASSES 46
#define NEG_SLOPE 0.2f
#define KP 832          // IN_CH padded to multiple of 64

typedef __attribute__((ext_vector_type(8))) short bf16x8;
typedef __attribute__((ext_vector_type(4))) float f32x4;

__device__ __forceinline__ float leaky(float v) { return v > 0.f ? v : NEG_SLOPE * v; }

__device__ __forceinline__ unsigned short f2bf(float f) {  // RNE bf16
  unsigned u = __float_as_uint(f);
  unsigned r = u + 0x7fff + ((u >> 16) & 1);
  return (unsigned short)(r >> 16);
}
__device__ __forceinline__ float bf2f(short s) {
  return __uint_as_float(((unsigned)(unsigned short)s) << 16);
}

#define GLOAD_LDS16(g, l)                                                        \
  __builtin_amdgcn_global_load_lds((const __attribute__((address_space(1))) unsigned*)(g), \
                                   (__attribute__((address_space(3))) unsigned*)(l), 16, 0, 0)

// ---------------- conversion: x fp32 [M][814] -> Ab bf16 [M][832] (zero-pad) ----------------
__global__ __launch_bounds__(256) void convert_x(const float* __restrict__ x,
                                                 unsigned short* __restrict__ Ab) {
  const int row = blockIdx.x;
  const int c = threadIdx.x * 4;
  if (c >= KP) return;
  const float* xr = x + (size_t)row * IN_CH;
  float v[4] = {0.f, 0.f, 0.f, 0.f};
  if (c + 3 < IN_CH) {  // row base is 8B-aligned (814*4B); use float2 pairs
    float2 u0 = *(const float2*)(xr + c);
    float2 u1 = *(const float2*)(xr + c + 2);
    v[0] = u0.x; v[1] = u0.y; v[2] = u1.x; v[3] = u1.y;
  } else {
#pragma unroll
    for (int k = 0; k < 4; k++) if (c + k < IN_CH) v[k] = xr[c + k];
  }
  ushort4 o = make_ushort4(f2bf(v[0]), f2bf(v[1]), f2bf(v[2]), f2bf(v[3]));
  *(ushort4*)&Ab[(size_t)row * KP + c] = o;
}

// ---------------- W1 fp32 [814][512] -> Bt bf16 [512][832] via LDS tile transpose ----------------
__global__ __launch_bounds__(256) void convert_w1t(const float* __restrict__ W1,
                                                   unsigned short* __restrict__ Bt) {
  __shared__ float tile[32][33];
  const int n0 = blockIdx.x * 32;          // output-col block (16 blocks)
  const int k0 = blockIdx.y * 32;          // k block (26 blocks)
  const int tx = threadIdx.x & 31, ty = threadIdx.x >> 5;  // 32 x 8
#pragma unroll
  for (int i = 0; i < 32; i += 8) {
    const int k = k0 + ty + i;
    tile[ty + i][tx] = (k < IN_CH) ? W1[(size_t)k * 512 + n0 + tx] : 0.f;
  }
  __syncthreads();
#pragma unroll
  for (int i = 0; i < 32; i += 8) {
    const int n = n0 + ty + i;
    Bt[(size_t)n * KP + k0 + tx] = f2bf(tile[tx][ty + i]);
  }
}

// ---------------- W2 fp32 [512][128] -> Bt2 bf16 [128][512] (transposed; L2-resident) ----------------
__global__ __launch_bounds__(256) void convert_w2t(const float* __restrict__ W2,
                                                   unsigned short* __restrict__ Bt2) {
  const int n = blockIdx.x;  // output column 0..127
  unsigned short* br = Bt2 + (size_t)n * 512;
  for (int k = threadIdx.x; k < 512; k += 256) br[k] = f2bf(W2[(size_t)k * 128 + n]);
}

// ---------------- bf16 MFMA GEMM: C[M][CPITCH] = A[M][KPITCH] @ B[N][KPITCH]^T ----------------
// 128x128 tile, BK=64, 4 waves (2x2 of 64x64), global_load_lds staging,
// 2-phase double-buffer (STAGE t+1 issued before compute t; one barrier per K-step).
// Grid: blockIdx.x = col block (fastest -> A row-panel L2/L3 reuse), blockIdx.y = row block.
template<int KPITCH, int CPITCH, bool OUTBF>
__global__ __launch_bounds__(256) void gemm_mfma(const unsigned short* __restrict__ A,
                                                 const unsigned short* __restrict__ B,
                                                 void* __restrict__ Cv) {
  constexpr int NT = KPITCH / 64;
  __shared__ unsigned short sA[2][8 * 128 * 8];  // 2 x 16 KB
  __shared__ unsigned short sB[2][8 * 128 * 8];  // 2 x 16 KB
  const int tid = threadIdx.x;
  const int w = tid >> 6, lane = tid & 63;
  const int row0 = blockIdx.y * 128;
  const int col0 = blockIdx.x * 128;
  const int wr = w >> 1, wc = w & 1;

  f32x4 acc[4][4];
#pragma unroll
  for (int mi = 0; mi < 4; mi++)
#pragma unroll
    for (int nj = 0; nj < 4; nj++) acc[mi][nj] = (f32x4){0.f, 0.f, 0.f, 0.f};

  long a_off[4], b_off[4];
  int lds_base[4];
#pragma unroll
  for (int c = 0; c < 4; c++) {
    const int s = (w * 4 + c) * 64 + lane;
    const int kg = s >> 7, r = s & 127;
    int arow = row0 + r; if (arow >= N_NODES) arow = N_NODES - 1;  // clamp (never stored)
    a_off[c] = (long)arow * KPITCH + kg * 8;
    b_off[c] = (long)(col0 + r) * KPITCH + kg * 8;
    lds_base[c] = (w * 4 + c) * 64 * 8;  // shorts
  }
  int aoff[4][2], boff[4][2];
#pragma unroll
  for (int i = 0; i < 4; i++)
#pragma unroll
    for (int ks = 0; ks < 2; ks++) {
      aoff[i][ks] = ((ks * 4 + (lane >> 4)) * 128 + wr * 64 + i * 16 + (lane & 15)) * 8;
      boff[i][ks] = ((ks * 4 + (lane >> 4)) * 128 + wc * 64 + i * 16 + (lane & 15)) * 8;
    }

#define STAGE(kt, b)                                                     \
  {                                                                      \
    const int kbase = (kt) * 64;                                         \
    _Pragma("unroll")                                                    \
    for (int c = 0; c < 4; c++) {                                        \
      GLOAD_LDS16(A + (a_off[c] + kbase), &sA[b][lds_base[c]]);          \
      GLOAD_LDS16(B + (b_off[c] + kbase), &sB[b][lds_base[c]]);          \
    }                                                                    \
  }

#define COMPUTE(b)                                                                   \
  {                                                                                  \
    bf16x8 af[4][2], bfr[4][2];                                                      \
    _Pragma("unroll")                                                                \
    for (int mi = 0; mi < 4; mi++)                                                   \
      _Pragma("unroll")                                                              \
      for (int ks = 0; ks < 2; ks++) af[mi][ks] = *(const bf16x8*)&sA[b][aoff[mi][ks]]; \
    _Pragma("unroll")                                                                \
    for (int nj = 0; nj < 4; nj++)                                                   \
      _Pragma("unroll")                                                              \
      for (int ks = 0; ks < 2; ks++) bfr[nj][ks] = *(const bf16x8*)&sB[b][boff[nj][ks]]; \
    _Pragma("unroll")                                                                \
    for (int mi = 0; mi < 4; mi++)                                                   \
      _Pragma("unroll")                                                              \
      for (int nj = 0; nj < 4; nj++) {                                               \
        acc[mi][nj] = __builtin_amdgcn_mfma_f32_16x16x32_bf16(af[mi][0], bfr[nj][0], acc[mi][nj], 0, 0, 0); \
        acc[mi][nj] = __builtin_amdgcn_mfma_f32_16x16x32_bf16(af[mi][1], bfr[nj][1], acc[mi][nj], 0, 0, 0); \
      }                                                                              \
  }

  STAGE(0, 0);
  __syncthreads();           // compiler drains vmcnt(0) here: buf0 ready
  int cur = 0;
  for (int kt = 0; kt < NT - 1; ++kt) {
    STAGE(kt + 1, cur ^ 1);  // prefetch flies under this step's ds_read+MFMA
    COMPUTE(cur);
    __syncthreads();         // drains prefetch + ensures reads done before overwrite
    cur ^= 1;
  }
  COMPUTE(cur);
#undef STAGE
#undef COMPUTE

  // store: D col = lane&15, row = (lane>>4)*4 + reg  [HW-verified round 4/5]
  const int r4 = (lane >> 4) * 4;
  const int cc = lane & 15;
#pragma unroll
  for (int mi = 0; mi < 4; mi++) {
#pragma unroll
    for (int r = 0; r < 4; r++) {
      const int gr = row0 + wr * 64 + mi * 16 + r4 + r;
      if (gr < N_NODES) {
        if (OUTBF) {
          unsigned short* cp = (unsigned short*)Cv + (size_t)gr * CPITCH + col0 + wc * 64 + cc;
#pragma unroll
          for (int nj = 0; nj < 4; nj++) cp[nj * 16] = f2bf(acc[mi][nj][r]);
        } else {
          float* cp = (float*)Cv + (size_t)gr * CPITCH + col0 + wc * 64 + cc;
#pragma unroll
          for (int nj = 0; nj < 4; nj++) cp[nj * 16] = acc[mi][nj][r];
        }
      }
    }
  }
}

// ---------------- attention logit prep, layer 1 (h1 bf16; lane owns 8 contiguous ch) ----------------
__global__ __launch_bounds__(256) void attn_prep1(const unsigned short* __restrict__ h1b,
                                                  const float* __restrict__ a_src,
                                                  const float* __restrict__ a_dst,
                                                  float* __restrict__ als,
                                                  float* __restrict__ ald) {
  const int n = blockIdx.x * 4 + (threadIdx.x >> 6);
  const int lane = threadIdx.x & 63;
  if (n >= N_NODES) return;
  const int c0 = lane * 8;                 // head = lane>>4 (8 ch never straddle 128)
  const bf16x8 hv = *(const bf16x8*)&h1b[(size_t)n * 512 + c0];
  float ps = 0.f, pd = 0.f;
#pragma unroll
  for (int j = 0; j < 8; j++) {
    const float f = bf2f(hv[j]);
    ps += f * a_src[c0 + j];
    pd += f * a_dst[c0 + j];
  }
#pragma unroll
  for (int off = 8; off; off >>= 1) {      // reduce within 16-lane head group
    ps += __shfl_xor(ps, off);
    pd += __shfl_xor(pd, off);
  }
  if ((lane & 15) == 0) {
    als[n * 4 + (lane >> 4)] = ps;
    ald[n * 4 + (lane >> 4)] = pd;
  }
}

// ---------------- attention logit prep, layer 2 (h2 fp32, 1 head) ----------------
__global__ __launch_bounds__(256) void attn_prep2(const float* __restrict__ h2,
                                                  const float* __restrict__ a_src,
                                                  const float* __restrict__ a_dst,
                                                  float* __restrict__ als,
                                                  float* __restrict__ ald) {
  const int n = blockIdx.x * 4 + (threadIdx.x >> 6);
  const int lane = threadIdx.x & 63;
  if (n >= N_NODES) return;
  const float* hr = h2 + (size_t)n * 128;
  float h0 = hr[lane], h1v = hr[lane + 64];
  float ps = h0 * a_src[lane] + h1v * a_src[lane + 64];
  float pd = h0 * a_dst[lane] + h1v * a_dst[lane + 64];
#pragma unroll
  for (int off = 32; off; off >>= 1) {
    ps += __shfl_xor(ps, off);
    pd += __shfl_xor(pd, off);
  }
  if (lane == 0) { als[n] = ps; ald[n] = pd; }
}

// ---------------- CSR build ----------------
__global__ void init_misc(int* deg, float* pooled, float* cnts) {
  const int i = blockIdx.x * 256 + threadIdx.x;
  if (i < N_NODES) deg[i] = 1;  // self-loop
  if (i < NUM_GRAPHS * HID) pooled[i] = 0.f;
  if (i < NUM_GRAPHS) cnts[i] = 0.f;
}

__global__ void hist_kernel(const int* __restrict__ dst, int* deg) {
  const int e = blockIdx.x * 256 + threadIdx.x;
  if (e < N_EDGES) atomicAdd(&deg[dst[e]], 1);
}

// two-level scan
__global__ __launch_bounds__(256) void scan_block_sum(const int* __restrict__ deg, int* bsum) {
  __shared__ int sd[256];
  const int t = threadIdx.x;
  const int i = blockIdx.x * 256 + t;
  sd[t] = (i < N_NODES) ? deg[i] : 0;
  __syncthreads();
  for (int s = 128; s; s >>= 1) { if (t < s) sd[t] += sd[t + s]; __syncthreads(); }
  if (t == 0) bsum[blockIdx.x] = sd[0];
}

__global__ __launch_bounds__(256) void scan_base(const int* __restrict__ bsum, int* bbase, int* offsets) {
  __shared__ int tmp[256];
  const int t = threadIdx.x;
  const int nb = (N_NODES + 255) / 256;
  const int v = (t < nb) ? bsum[t] : 0;
  tmp[t] = v;
  __syncthreads();
  for (int off = 1; off < 256; off <<= 1) {
    int a = (t >= off) ? tmp[t - off] : 0;
    __syncthreads();
    tmp[t] += a;
    __syncthreads();
  }
  if (t < nb) bbase[t] = tmp[t] - v;
  if (t == 255) offsets[N_NODES] = tmp[255];
}

__global__ __launch_bounds__(256) void scan_final(const int* __restrict__ deg,
                                                  const int* __restrict__ bbase,
                                                  int* offsets, int* cursor) {
  __shared__ int tmp[256];
  const int t = threadIdx.x;
  const int i = blockIdx.x * 256 + t;
  const int v = (i < N_NODES) ? deg[i] : 0;
  tmp[t] = v;
  __syncthreads();
  for (int off = 1; off < 256; off <<= 1) {
    int a = (t >= off) ? tmp[t - off] : 0;
    __syncthreads();
    tmp[t] += a;
    __syncthreads();
  }
  if (i < N_NODES) {
    const int excl = bbase[blockIdx.x] + tmp[t] - v;
    offsets[i] = excl;
    cursor[i] = excl;
  }
}

__global__ void scatter_kernel(const int* __restrict__ src, const int* __restrict__ dst,
                               int* cursor, int* __restrict__ srcs) {
  const int e = blockIdx.x * 256 + threadIdx.x;
  if (e >= N_EDGES + N_NODES) return;
  int s, d;
  if (e < N_EDGES) { s = src[e]; d = dst[e]; }
  else { s = e - N_EDGES; d = s; }
  const int p = atomicAdd(&cursor[d], 1);
  srcs[p] = s;
}

// ---------------- GAT aggregation layer 1 (bf16 in/out; lane owns 8 contiguous ch) ----------------
__global__ __launch_bounds__(256) void aggregate1(const unsigned short* __restrict__ h1b,
                                                  const float* __restrict__ als,
                                                  const float* __restrict__ ald,
                                                  const int* __restrict__ offsets,
                                                  const int* __restrict__ srcs,
                                                  const float* __restrict__ b1,
                                                  unsigned short* __restrict__ x2b) {
  const int n = blockIdx.x * 4 + (threadIdx.x >> 6);
  const int lane = threadIdx.x & 63;
  if (n >= N_NODES) return;
  const int beg = offsets[n], end = offsets[n + 1];
  const int h = lane >> 4;
  const int c0 = lane * 8;
  const float aldh = ald[n * 4 + h];
  float m = -1e30f;
  for (int p = beg; p < end; p++)
    m = fmaxf(m, leaky(als[srcs[p] * 4 + h] + aldh));
  float den = 0.f;
  float acc[8] = {0, 0, 0, 0, 0, 0, 0, 0};
  for (int p = beg; p < end; p++) {
    const int s = srcs[p];
    const float w = __expf(leaky(als[s * 4 + h] + aldh) - m);
    den += w;
    const bf16x8 hv = *(const bf16x8*)&h1b[(size_t)s * 512 + c0];
#pragma unroll
    for (int j = 0; j < 8; j++) acc[j] += w * bf2f(hv[j]);
  }
  bf16x8 o;
  const float inv = 1.f / den;
#pragma unroll
  for (int j = 0; j < 8; j++)
    o[j] = (short)f2bf(fmaxf(acc[j] * inv + b1[c0 + j], 0.f));
  *(bf16x8*)&x2b[(size_t)n * 512 + c0] = o;
}

// ---------------- GAT aggregation layer 2 (h2 fp32; lane owns 2 contiguous ch) ----------------
__global__ __launch_bounds__(256) void aggregate2(const float* __restrict__ h2,
                                                  const float* __restrict__ als,
                                                  const float* __restrict__ ald,
                                                  const int* __restrict__ offsets,
                                                  const int* __restrict__ srcs,
                                                  const float* __restrict__ b2,
                                                  float* __restrict__ out2) {
  const int n = blockIdx.x * 4 + (threadIdx.x >> 6);
  const int lane = threadIdx.x & 63;
  if (n >= N_NODES) return;
  const int beg = offsets[n], end = offsets[n + 1];
  const int c0 = lane * 2;
  const float aldn = ald[n];
  float m = -1e30f;
  for (int p = beg; p < end; p++) m = fmaxf(m, leaky(als[srcs[p]] + aldn));
  float den = 0.f, a0 = 0.f, a1 = 0.f;
  for (int p = beg; p < end; p++) {
    const int s = srcs[p];
    const float w = __expf(leaky(als[s] + aldn) - m);
    den += w;
    const float2 hv = *(const float2*)&h2[(size_t)s * 128 + c0];
    a0 += w * hv.x;
    a1 += w * hv.y;
  }
  const float inv = 1.f / den;
  float2 o = make_float2(fmaxf(a0 * inv + b2[c0], 0.f), fmaxf(a1 * inv + b2[c0 + 1], 0.f));
  *(float2*)&out2[(size_t)n * 128 + c0] = o;
}

// ---------------- global mean pool (batch sorted -> run-length accumulate) ----------------
__global__ __launch_bounds__(128) void pool_kernel(const float* __restrict__ out2,
                                                   const int* __restrict__ batch,
                                                   float* pooled, float* cnts) {
  const int t = threadIdx.x;
  const int base = blockIdx.x * 256;
  float acc = 0.f;
  float cnt = 0.f;
  int cur = -1;
  for (int i = 0; i < 256; i++) {
    const int n = base + i;
    if (n >= N_NODES) break;
    const int g = batch[n];
    if (g != cur) {
      if (cur >= 0) {
        atomicAdd(&pooled[cur * HID + t], acc);
        if (t == 0) atomicAdd(&cnts[cur], cnt);
      }
      acc = 0.f; cnt = 0.f; cur = g;
    }
    acc += out2[(size_t)n * HID + t];
    cnt += 1.f;
  }
  if (cur >= 0) {
    atomicAdd(&pooled[cur * HID + t], acc);
    if (t == 0) atomicAdd(&cnts[cur], cnt);
  }
}

// ---------------- MLP head ----------------
__global__ __launch_bounds__(64) void mlp_kernel(const float* __restrict__ pooled,
                                                 const float* __restrict__ cnts,
                                                 const float* __restrict__ fc1_w,
                                                 const float* __restrict__ fc1_b,
                                                 const float* __restrict__ fc2_w,
                                                 const float* __restrict__ fc2_b,
                                                 float* __restrict__ out) {
  __shared__ float pl[128];
  __shared__ float z[64];
  const int g = blockIdx.x, t = threadIdx.x;
  const float c = fmaxf(cnts[g], 1.0f);
  pl[t] = pooled[g * HID + t] / c;
  pl[t + 64] = pooled[g * HID + t + 64] / c;
  __syncthreads();
  float acc = fc1_b[t];
  for (int i = 0; i < 128; i++) acc += pl[i] * fc1_w[i * 64 + t];
  z[t] = fmaxf(acc, 0.f);
  __syncthreads();
  if (t < NUM_CLASSES) {
    float o = fc2_b[t];
    for (int i = 0; i < 64; i++) o += z[i] * fc2_w[i * NUM_CLASSES + t];
    out[g * NUM_CLASSES + t] = o;
  }
}

extern "C" void kernel_launch(void* const* d_in, const int* in_sizes, int n_in,
                              void* d_out, int out_size, void* d_ws, size_t ws_size,
                              hipStream_t stream) {
  const float* x       = (const float*)d_in[0];
  const int*   ei      = (const int*)d_in[1];
  const int*   batch   = (const int*)d_in[2];
  const float* W1      = (const float*)d_in[3];
  const float* a_src1  = (const float*)d_in[4];
  const float* a_dst1  = (const float*)d_in[5];
  const float* b1      = (const float*)d_in[6];
  const float* W2      = (const float*)d_in[7];
  const float* a_src2  = (const float*)d_in[8];
  const float* a_dst2  = (const float*)d_in[9];
  const float* b2      = (const float*)d_in[10];
  const float* fc1_w   = (const float*)d_in[11];
  const float* fc1_b   = (const float*)d_in[12];
  const float* fc2_w   = (const float*)d_in[13];
  const float* fc2_b   = (const float*)d_in[14];
  float* out = (float*)d_out;

  const int* e_src = ei;
  const int* e_dst = ei + N_EDGES;

  // workspace layout (units: floats from d_ws base)
  float* wsf = (float*)d_ws;
  unsigned short* h1b = (unsigned short*)wsf;              // 50000*512 bf16 = 12.8M floats
  unsigned short* Ab  = (unsigned short*)(wsf + 12800000); // 50000*832 bf16 = 20.8M floats
  unsigned short* x2b = (unsigned short*)(wsf + 33600000); // 50000*512 bf16 = 12.8M floats
  unsigned short* Bt  = (unsigned short*)(wsf + 46400000); // 512*832 bf16 = 212,992 floats
  unsigned short* Bt2 = (unsigned short*)(wsf + 46613000); // 128*512 bf16 = 32,768 floats
  float* als1 = wsf + 46646000;               // 200,000
  float* ald1 = als1 + 200000;                // 200,000
  float* als2 = ald1 + 200000;                // 50,000
  float* ald2 = als2 + 50000;                 // 50,000
  float* pooled = ald2 + 50000;               // 8,192
  float* cnts = pooled + 8192;                // 64
  int* deg     = (int*)(cnts + 64);           // 50,000
  int* offsets = deg + 50000;                 // 50,001
  int* cursor  = offsets + 50001;             // 50,000
  int* srcs    = cursor + 50000;              // 450,000
  int* bsum    = srcs + 450000;               // 196
  int* bbase   = bsum + 200;                  // 196
  // overlays into Ab region (Ab dead after gemm1):
  float* h2   = wsf + 12800000;               // 6.4M floats
  float* out2 = wsf + 19200000;               // 6.4M floats

  const int NB = (N_NODES + 255) / 256;  // 196

  // CSR build + inits
  init_misc<<<NB, 256, 0, stream>>>(deg, pooled, cnts);
  hist_kernel<<<(N_EDGES + 255) / 256, 256, 0, stream>>>(e_dst, deg);
  scan_block_sum<<<NB, 256, 0, stream>>>(deg, bsum);
  scan_base<<<1, 256, 0, stream>>>(bsum, bbase, offsets);
  scan_final<<<NB, 256, 0, stream>>>(deg, bbase, offsets, cursor);
  scatter_kernel<<<(N_EDGES + N_NODES + 255) / 256, 256, 0, stream>>>(e_src, e_dst, cursor, srcs);

  // layer 1: bf16 conversion + MFMA GEMM (h1 bf16)
  convert_x<<<N_NODES, 256, 0, stream>>>(x, Ab);
  convert_w1t<<<dim3(16, 26), 256, 0, stream>>>(W1, Bt);
  gemm_mfma<KP, 512, true><<<dim3(4, 391), 256, 0, stream>>>(Ab, Bt, (void*)h1b);
  attn_prep1<<<12500, 256, 0, stream>>>(h1b, a_src1, a_dst1, als1, ald1);
  aggregate1<<<12500, 256, 0, stream>>>(h1b, als1, ald1, offsets, srcs, b1, x2b);

  // layer 2: bf16 MFMA GEMM (h2 fp32)
  convert_w2t<<<128, 256, 0, stream>>>(W2, Bt2);
  gemm_mfma<512, 128, false><<<dim3(1, 391), 256, 0, stream>>>(x2b, Bt2, (void*)h2);
  attn_prep2<<<12500, 256, 0, stream>>>(h2, a_src2, a_dst2, als2, ald2);
  aggregate2<<<12500, 256, 0, stream>>>(h2, als2, ald2, offsets, srcs, b2, out2);

  // pool + MLP
  pool_kernel<<<NB, 128, 0, stream>>>(out2, batch, pooled, cnts);
  mlp_kernel<<<NUM_GRAPHS, 64, 0, stream>>>(pooled, cnts, fc1_w, fc1_b, fc2_w, fc2_b, out);
}

// Round 10
// 726.410 us; speedup vs baseline: 1.0217x; 1.0217x over previous
//
#include <hip/hip_runtime.h>
#include <hip/hip_bf16.h>

#define N_NODES 50000
#define N_EDGES 400000
#define IN_CH   814
#define HID     128
#define HEADS1  4
#define NUM_GRAPHS 64
#define NUM_CLASSES 46
#define NEG_SLOPE 0.2f
#define KP 832          // IN_CH padded to multiple of 64

typedef __attribute__((ext_vector_type(8))) short bf16x8;
typedef __attribute__((ext_vector_type(4))) float f32x4;

__device__ __forceinline__ float leaky(float v) { return v > 0.f ? v : NEG_SLOPE * v; }

__device__ __forceinline__ unsigned short f2bf(float f) {  // RNE bf16
  unsigned u = __float_as_uint(f);
  unsigned r = u + 0x7fff + ((u >> 16) & 1);
  return (unsigned short)(r >> 16);
}
__device__ __forceinline__ float bf2f(short s) {
  return __uint_as_float(((unsigned)(unsigned short)s) << 16);
}

#define GLOAD_LDS16(g, l)                                                        \
  __builtin_amdgcn_global_load_lds((const __attribute__((address_space(1))) unsigned*)(g), \
                                   (__attribute__((address_space(3))) unsigned*)(l), 16, 0, 0)

// ---------------- conversion: x fp32 [M][814] -> Ab bf16 [M][832] (zero-pad) ----------------
__global__ __launch_bounds__(256) void convert_x(const float* __restrict__ x,
                                                 unsigned short* __restrict__ Ab) {
  const int row = blockIdx.x;
  const int c = threadIdx.x * 4;
  if (c >= KP) return;
  const float* xr = x + (size_t)row * IN_CH;
  float v[4] = {0.f, 0.f, 0.f, 0.f};
  if (c + 3 < IN_CH) {  // row base is 8B-aligned (814*4B); use float2 pairs
    float2 u0 = *(const float2*)(xr + c);
    float2 u1 = *(const float2*)(xr + c + 2);
    v[0] = u0.x; v[1] = u0.y; v[2] = u1.x; v[3] = u1.y;
  } else {
#pragma unroll
    for (int k = 0; k < 4; k++) if (c + k < IN_CH) v[k] = xr[c + k];
  }
  ushort4 o = make_ushort4(f2bf(v[0]), f2bf(v[1]), f2bf(v[2]), f2bf(v[3]));
  *(ushort4*)&Ab[(size_t)row * KP + c] = o;
}

// ---------------- W1 fp32 [814][512] -> Bt bf16 [512][832] via LDS tile transpose ----------------
__global__ __launch_bounds__(256) void convert_w1t(const float* __restrict__ W1,
                                                   unsigned short* __restrict__ Bt) {
  __shared__ float tile[32][33];
  const int n0 = blockIdx.x * 32;          // output-col block (16 blocks)
  const int k0 = blockIdx.y * 32;          // k block (26 blocks)
  const int tx = threadIdx.x & 31, ty = threadIdx.x >> 5;  // 32 x 8
#pragma unroll
  for (int i = 0; i < 32; i += 8) {
    const int k = k0 + ty + i;
    tile[ty + i][tx] = (k < IN_CH) ? W1[(size_t)k * 512 + n0 + tx] : 0.f;
  }
  __syncthreads();
#pragma unroll
  for (int i = 0; i < 32; i += 8) {
    const int n = n0 + ty + i;
    Bt[(size_t)n * KP + k0 + tx] = f2bf(tile[tx][ty + i]);
  }
}

// ---------------- W2 fp32 [512][128] -> Bt2 bf16 [128][512] (transposed; L2-resident) ----------------
__global__ __launch_bounds__(256) void convert_w2t(const float* __restrict__ W2,
                                                   unsigned short* __restrict__ Bt2) {
  const int n = blockIdx.x;  // output column 0..127
  unsigned short* br = Bt2 + (size_t)n * 512;
  for (int k = threadIdx.x; k < 512; k += 256) br[k] = f2bf(W2[(size_t)k * 128 + n]);
}

// ---------------- bf16 MFMA GEMM + fused attention-logit epilogue ----------------
// C[M][CPITCH] = A[M][KPITCH] @ B[N][KPITCH]^T ; als/ald[row][col0>>7] = sum_c C*a_src/a_dst
// 128x128 tile, BK=64, 4 waves (2x2 of 64x64). 2-deep counted-vmcnt pipeline (T4):
// 16 loads in flight; vmcnt(8) + raw s_barrier per step; never drain to 0 mid-loop.
template<int KPITCH, int CPITCH, bool OUTBF>
__global__ __launch_bounds__(256) void gemm_mfma(const unsigned short* __restrict__ A,
                                                 const unsigned short* __restrict__ B,
                                                 void* __restrict__ Cv,
                                                 const float* __restrict__ as_,
                                                 const float* __restrict__ ad_,
                                                 float* __restrict__ als,
                                                 float* __restrict__ ald) {
  constexpr int NT = KPITCH / 64;
  __shared__ unsigned short sA[2][8 * 128 * 8];  // 2 x 16 KB
  __shared__ unsigned short sB[2][8 * 128 * 8];  // 2 x 16 KB
  const int tid = threadIdx.x;
  const int w = tid >> 6, lane = tid & 63;
  const int row0 = blockIdx.y * 128;
  const int col0 = blockIdx.x * 128;
  const int wr = w >> 1, wc = w & 1;

  f32x4 acc[4][4];
#pragma unroll
  for (int mi = 0; mi < 4; mi++)
#pragma unroll
    for (int nj = 0; nj < 4; nj++) acc[mi][nj] = (f32x4){0.f, 0.f, 0.f, 0.f};

  long a_off[4], b_off[4];
  int lds_base[4];
#pragma unroll
  for (int c = 0; c < 4; c++) {
    const int s = (w * 4 + c) * 64 + lane;
    const int kg = s >> 7, r = s & 127;
    int arow = row0 + r; if (arow >= N_NODES) arow = N_NODES - 1;  // clamp (never stored)
    a_off[c] = (long)arow * KPITCH + kg * 8;
    b_off[c] = (long)(col0 + r) * KPITCH + kg * 8;
    lds_base[c] = (w * 4 + c) * 64 * 8;  // shorts
  }
  int aoff[4][2], boff[4][2];
#pragma unroll
  for (int i = 0; i < 4; i++)
#pragma unroll
    for (int ks = 0; ks < 2; ks++) {
      aoff[i][ks] = ((ks * 4 + (lane >> 4)) * 128 + wr * 64 + i * 16 + (lane & 15)) * 8;
      boff[i][ks] = ((ks * 4 + (lane >> 4)) * 128 + wc * 64 + i * 16 + (lane & 15)) * 8;
    }

#define STAGE(kt, b)                                                     \
  {                                                                      \
    const int kbase = (kt) * 64;                                         \
    _Pragma("unroll")                                                    \
    for (int c = 0; c < 4; c++) {                                        \
      GLOAD_LDS16(A + (a_off[c] + kbase), &sA[b][lds_base[c]]);          \
      GLOAD_LDS16(B + (b_off[c] + kbase), &sB[b][lds_base[c]]);          \
    }                                                                    \
  }

#define COMPUTE(b)                                                                   \
  {                                                                                  \
    bf16x8 af[4][2], bfr[4][2];                                                      \
    _Pragma("unroll")                                                                \
    for (int mi = 0; mi < 4; mi++)                                                   \
      _Pragma("unroll")                                                              \
      for (int ks = 0; ks < 2; ks++) af[mi][ks] = *(const bf16x8*)&sA[b][aoff[mi][ks]]; \
    _Pragma("unroll")                                                                \
    for (int nj = 0; nj < 4; nj++)                                                   \
      _Pragma("unroll")                                                              \
      for (int ks = 0; ks < 2; ks++) bfr[nj][ks] = *(const bf16x8*)&sB[b][boff[nj][ks]]; \
    _Pragma("unroll")                                                                \
    for (int mi = 0; mi < 4; mi++)                                                   \
      _Pragma("unroll")                                                              \
      for (int nj = 0; nj < 4; nj++) {                                               \
        acc[mi][nj] = __builtin_amdgcn_mfma_f32_16x16x32_bf16(af[mi][0], bfr[nj][0], acc[mi][nj], 0, 0, 0); \
        acc[mi][nj] = __builtin_amdgcn_mfma_f32_16x16x32_bf16(af[mi][1], bfr[nj][1], acc[mi][nj], 0, 0, 0); \
      }                                                                              \
  }

  STAGE(0, 0);
  STAGE(1, 1);
  int cur = 0;
  for (int kt = 0; kt < NT; ++kt) {
    if (kt < NT - 1) {
      asm volatile("s_waitcnt vmcnt(8)" ::: "memory");   // own buf[cur] fills done; next tile stays in flight
    } else {
      asm volatile("s_waitcnt vmcnt(0)" ::: "memory");   // last tile: nothing newer
    }
    __builtin_amdgcn_s_barrier();                        // all waves' fills done
    __builtin_amdgcn_sched_barrier(0);
    COMPUTE(cur);
    if (kt + 2 < NT) {
      asm volatile("s_waitcnt lgkmcnt(0)" ::: "memory"); // all own ds_reads of buf[cur] complete
      __builtin_amdgcn_s_barrier();                      // everyone done reading -> safe to refill
      __builtin_amdgcn_sched_barrier(0);
      STAGE(kt + 2, cur);
    }
    cur ^= 1;
  }
#undef STAGE
#undef COMPUTE

  // store: D col = lane&15, row = (lane>>4)*4 + reg  [HW-verified round 4/5]
  const int r4 = (lane >> 4) * 4;
  const int cc = lane & 15;
#pragma unroll
  for (int mi = 0; mi < 4; mi++) {
#pragma unroll
    for (int r = 0; r < 4; r++) {
      const int gr = row0 + wr * 64 + mi * 16 + r4 + r;
      if (gr < N_NODES) {
        if (OUTBF) {
          unsigned short* cp = (unsigned short*)Cv + (size_t)gr * CPITCH + col0 + wc * 64 + cc;
#pragma unroll
          for (int nj = 0; nj < 4; nj++) cp[nj * 16] = f2bf(acc[mi][nj][r]);
        } else {
          float* cp = (float*)Cv + (size_t)gr * CPITCH + col0 + wc * 64 + cc;
#pragma unroll
          for (int nj = 0; nj < 4; nj++) cp[nj * 16] = acc[mi][nj][r];
        }
      }
    }
  }

  // ---- fused attention-logit epilogue (this block covers exactly one head) ----
  __syncthreads();                       // all LDS reads done; sA reusable
  float* pld = (float*)sA;               // [2 s/d][2 wc][128 rowLocal] = 2 KB
#pragma unroll
  for (int mi = 0; mi < 4; mi++) {
#pragma unroll
    for (int r = 0; r < 4; r++) {
      float s = 0.f, d = 0.f;
#pragma unroll
      for (int nj = 0; nj < 4; nj++) {
        const float v = acc[mi][nj][r];
        const int gc = col0 + wc * 64 + nj * 16 + cc;
        s += v * as_[gc];
        d += v * ad_[gc];
      }
#pragma unroll
      for (int off = 8; off; off >>= 1) {  // reduce over cc (16 lanes)
        s += __shfl_xor(s, off);
        d += __shfl_xor(d, off);
      }
      if ((lane & 15) == 0) {
        const int rowL = wr * 64 + mi * 16 + r4 + r;
        pld[0 * 256 + wc * 128 + rowL] = s;
        pld[1 * 256 + wc * 128 + rowL] = d;
      }
    }
  }
  __syncthreads();
  if (tid < 128) {
    const int gr = row0 + tid;
    if (gr < N_NODES) {
      constexpr int NH = CPITCH / 128;
      const int hd = col0 >> 7;
      als[(size_t)gr * NH + hd] = pld[tid] + pld[128 + tid];
      ald[(size_t)gr * NH + hd] = pld[256 + tid] + pld[256 + 128 + tid];
    }
  }
}

// ---------------- CSR build ----------------
__global__ void init_misc(int* deg, float* pooled, float* cnts) {
  const int i = blockIdx.x * 256 + threadIdx.x;
  if (i < N_NODES) deg[i] = 1;  // self-loop
  if (i < NUM_GRAPHS * HID) pooled[i] = 0.f;
  if (i < NUM_GRAPHS) cnts[i] = 0.f;
}

__global__ void hist_kernel(const int* __restrict__ dst, int* deg) {
  const int e = blockIdx.x * 256 + threadIdx.x;
  if (e < N_EDGES) atomicAdd(&deg[dst[e]], 1);
}

// two-level scan
__global__ __launch_bounds__(256) void scan_block_sum(const int* __restrict__ deg, int* bsum) {
  __shared__ int sd[256];
  const int t = threadIdx.x;
  const int i = blockIdx.x * 256 + t;
  sd[t] = (i < N_NODES) ? deg[i] : 0;
  __syncthreads();
  for (int s = 128; s; s >>= 1) { if (t < s) sd[t] += sd[t + s]; __syncthreads(); }
  if (t == 0) bsum[blockIdx.x] = sd[0];
}

__global__ __launch_bounds__(256) void scan_base(const int* __restrict__ bsum, int* bbase, int* offsets) {
  __shared__ int tmp[256];
  const int t = threadIdx.x;
  const int nb = (N_NODES + 255) / 256;
  const int v = (t < nb) ? bsum[t] : 0;
  tmp[t] = v;
  __syncthreads();
  for (int off = 1; off < 256; off <<= 1) {
    int a = (t >= off) ? tmp[t - off] : 0;
    __syncthreads();
    tmp[t] += a;
    __syncthreads();
  }
  if (t < nb) bbase[t] = tmp[t] - v;
  if (t == 255) offsets[N_NODES] = tmp[255];
}

__global__ __launch_bounds__(256) void scan_final(const int* __restrict__ deg,
                                                  const int* __restrict__ bbase,
                                                  int* offsets, int* cursor) {
  __shared__ int tmp[256];
  const int t = threadIdx.x;
  const int i = blockIdx.x * 256 + t;
  const int v = (i < N_NODES) ? deg[i] : 0;
  tmp[t] = v;
  __syncthreads();
  for (int off = 1; off < 256; off <<= 1) {
    int a = (t >= off) ? tmp[t - off] : 0;
    __syncthreads();
    tmp[t] += a;
    __syncthreads();
  }
  if (i < N_NODES) {
    const int excl = bbase[blockIdx.x] + tmp[t] - v;
    offsets[i] = excl;
    cursor[i] = excl;
  }
}

__global__ void scatter_kernel(const int* __restrict__ src, const int* __restrict__ dst,
                               int* cursor, int* __restrict__ srcs) {
  const int e = blockIdx.x * 256 + threadIdx.x;
  if (e >= N_EDGES + N_NODES) return;
  int s, d;
  if (e < N_EDGES) { s = src[e]; d = dst[e]; }
  else { s = e - N_EDGES; d = s; }
  const int p = atomicAdd(&cursor[d], 1);
  srcs[p] = s;
}

// ---------------- GAT aggregation layer 1 (bf16 in/out; lane owns 8 contiguous ch) ----------------
__global__ __launch_bounds__(256) void aggregate1(const unsigned short* __restrict__ h1b,
                                                  const float* __restrict__ als,
                                                  const float* __restrict__ ald,
                                                  const int* __restrict__ offsets,
                                                  const int* __restrict__ srcs,
                                                  const float* __restrict__ b1,
                                                  unsigned short* __restrict__ x2b) {
  const int n = blockIdx.x * 4 + (threadIdx.x >> 6);
  const int lane = threadIdx.x & 63;
  if (n >= N_NODES) return;
  const int beg = offsets[n], end = offsets[n + 1];
  const int h = lane >> 4;
  const int c0 = lane * 8;
  const float aldh = ald[n * 4 + h];
  float m = -1e30f;
  for (int p = beg; p < end; p++)
    m = fmaxf(m, leaky(als[srcs[p] * 4 + h] + aldh));
  float den = 0.f;
  float acc[8] = {0, 0, 0, 0, 0, 0, 0, 0};
  for (int p = beg; p < end; p++) {
    const int s = srcs[p];
    const float w = __expf(leaky(als[s * 4 + h] + aldh) - m);
    den += w;
    const bf16x8 hv = *(const bf16x8*)&h1b[(size_t)s * 512 + c0];
#pragma unroll
    for (int j = 0; j < 8; j++) acc[j] += w * bf2f(hv[j]);
  }
  bf16x8 o;
  const float inv = 1.f / den;
#pragma unroll
  for (int j = 0; j < 8; j++)
    o[j] = (short)f2bf(fmaxf(acc[j] * inv + b1[c0 + j], 0.f));
  *(bf16x8*)&x2b[(size_t)n * 512 + c0] = o;
}

// ---------------- GAT aggregation layer 2 (h2 fp32; lane owns 2 contiguous ch) ----------------
__global__ __launch_bounds__(256) void aggregate2(const float* __restrict__ h2,
                                                  const float* __restrict__ als,
                                                  const float* __restrict__ ald,
                                                  const int* __restrict__ offsets,
                                                  const int* __restrict__ srcs,
                                                  const float* __restrict__ b2,
                                                  float* __restrict__ out2) {
  const int n = blockIdx.x * 4 + (threadIdx.x >> 6);
  const int lane = threadIdx.x & 63;
  if (n >= N_NODES) return;
  const int beg = offsets[n], end = offsets[n + 1];
  const int c0 = lane * 2;
  const float aldn = ald[n];
  float m = -1e30f;
  for (int p = beg; p < end; p++) m = fmaxf(m, leaky(als[srcs[p]] + aldn));
  float den = 0.f, a0 = 0.f, a1 = 0.f;
  for (int p = beg; p < end; p++) {
    const int s = srcs[p];
    const float w = __expf(leaky(als[s] + aldn) - m);
    den += w;
    const float2 hv = *(const float2*)&h2[(size_t)s * 128 + c0];
    a0 += w * hv.x;
    a1 += w * hv.y;
  }
  const float inv = 1.f / den;
  float2 o = make_float2(fmaxf(a0 * inv + b2[c0], 0.f), fmaxf(a1 * inv + b2[c0 + 1], 0.f));
  *(float2*)&out2[(size_t)n * 128 + c0] = o;
}

// ---------------- global mean pool (batch sorted -> run-length accumulate) ----------------
__global__ __launch_bounds__(128) void pool_kernel(const float* __restrict__ out2,
                                                   const int* __restrict__ batch,
                                                   float* pooled, float* cnts) {
  const int t = threadIdx.x;
  const int base = blockIdx.x * 256;
  float acc = 0.f;
  float cnt = 0.f;
  int cur = -1;
  for (int i = 0; i < 256; i++) {
    const int n = base + i;
    if (n >= N_NODES) break;
    const int g = batch[n];
    if (g != cur) {
      if (cur >= 0) {
        atomicAdd(&pooled[cur * HID + t], acc);
        if (t == 0) atomicAdd(&cnts[cur], cnt);
      }
      acc = 0.f; cnt = 0.f; cur = g;
    }
    acc += out2[(size_t)n * HID + t];
    cnt += 1.f;
  }
  if (cur >= 0) {
    atomicAdd(&pooled[cur * HID + t], acc);
    if (t == 0) atomicAdd(&cnts[cur], cnt);
  }
}

// ---------------- MLP head ----------------
__global__ __launch_bounds__(64) void mlp_kernel(const float* __restrict__ pooled,
                                                 const float* __restrict__ cnts,
                                                 const float* __restrict__ fc1_w,
                                                 const float* __restrict__ fc1_b,
                                                 const float* __restrict__ fc2_w,
                                                 const float* __restrict__ fc2_b,
                                                 float* __restrict__ out) {
  __shared__ float pl[128];
  __shared__ float z[64];
  const int g = blockIdx.x, t = threadIdx.x;
  const float c = fmaxf(cnts[g], 1.0f);
  pl[t] = pooled[g * HID + t] / c;
  pl[t + 64] = pooled[g * HID + t + 64] / c;
  __syncthreads();
  float acc = fc1_b[t];
  for (int i = 0; i < 128; i++) acc += pl[i] * fc1_w[i * 64 + t];
  z[t] = fmaxf(acc, 0.f);
  __syncthreads();
  if (t < NUM_CLASSES) {
    float o = fc2_b[t];
    for (int i = 0; i < 64; i++) o += z[i] * fc2_w[i * NUM_CLASSES + t];
    out[g * NUM_CLASSES + t] = o;
  }
}

extern "C" void kernel_launch(void* const* d_in, const int* in_sizes, int n_in,
                              void* d_out, int out_size, void* d_ws, size_t ws_size,
                              hipStream_t stream) {
  const float* x       = (const float*)d_in[0];
  const int*   ei      = (const int*)d_in[1];
  const int*   batch   = (const int*)d_in[2];
  const float* W1      = (const float*)d_in[3];
  const float* a_src1  = (const float*)d_in[4];
  const float* a_dst1  = (const float*)d_in[5];
  const float* b1      = (const float*)d_in[6];
  const float* W2      = (const float*)d_in[7];
  const float* a_src2  = (const float*)d_in[8];
  const float* a_dst2  = (const float*)d_in[9];
  const float* b2      = (const float*)d_in[10];
  const float* fc1_w   = (const float*)d_in[11];
  const float* fc1_b   = (const float*)d_in[12];
  const float* fc2_w   = (const float*)d_in[13];
  const float* fc2_b   = (const float*)d_in[14];
  float* out = (float*)d_out;

  const int* e_src = ei;
  const int* e_dst = ei + N_EDGES;

  // workspace layout (units: floats from d_ws base)
  float* wsf = (float*)d_ws;
  unsigned short* h1b = (unsigned short*)wsf;              // 50000*512 bf16 = 12.8M floats
  unsigned short* Ab  = (unsigned short*)(wsf + 12800000); // 50000*832 bf16 = 20.8M floats
  unsigned short* x2b = (unsigned short*)(wsf + 33600000); // 50000*512 bf16 = 12.8M floats
  unsigned short* Bt  = (unsigned short*)(wsf + 46400000); // 512*832 bf16 = 212,992 floats
  unsigned short* Bt2 = (unsigned short*)(wsf + 46613000); // 128*512 bf16 = 32,768 floats
  float* als1 = wsf + 46646000;               // 200,000
  float* ald1 = als1 + 200000;                // 200,000
  float* als2 = ald1 + 200000;                // 50,000
  float* ald2 = als2 + 50000;                 // 50,000
  float* pooled = ald2 + 50000;               // 8,192
  float* cnts = pooled + 8192;                // 64
  int* deg     = (int*)(cnts + 64);           // 50,000
  int* offsets = deg + 50000;                 // 50,001
  int* cursor  = offsets + 50001;             // 50,000
  int* srcs    = cursor + 50000;              // 450,000
  int* bsum    = srcs + 450000;               // 196
  int* bbase   = bsum + 200;                  // 196
  // overlays into Ab region (Ab dead after gemm1):
  float* h2   = wsf + 12800000;               // 6.4M floats
  float* out2 = wsf + 19200000;               // 6.4M floats

  const int NB = (N_NODES + 255) / 256;  // 196

  // CSR build + inits
  init_misc<<<NB, 256, 0, stream>>>(deg, pooled, cnts);
  hist_kernel<<<(N_EDGES + 255) / 256, 256, 0, stream>>>(e_dst, deg);
  scan_block_sum<<<NB, 256, 0, stream>>>(deg, bsum);
  scan_base<<<1, 256, 0, stream>>>(bsum, bbase, offsets);
  scan_final<<<NB, 256, 0, stream>>>(deg, bbase, offsets, cursor);
  scatter_kernel<<<(N_EDGES + N_NODES + 255) / 256, 256, 0, stream>>>(e_src, e_dst, cursor, srcs);

  // layer 1: bf16 conversion + MFMA GEMM (h1 bf16) with fused attn-logit epilogue
  convert_x<<<N_NODES, 256, 0, stream>>>(x, Ab);
  convert_w1t<<<dim3(16, 26), 256, 0, stream>>>(W1, Bt);
  gemm_mfma<KP, 512, true><<<dim3(4, 391), 256, 0, stream>>>(Ab, Bt, (void*)h1b,
                                                             a_src1, a_dst1, als1, ald1);
  aggregate1<<<12500, 256, 0, stream>>>(h1b, als1, ald1, offsets, srcs, b1, x2b);

  // layer 2: bf16 MFMA GEMM (h2 fp32) with fused attn-logit epilogue
  convert_w2t<<<128, 256, 0, stream>>>(W2, Bt2);
  gemm_mfma<512, 128, false><<<dim3(1, 391), 256, 0, stream>>>(x2b, Bt2, (void*)h2,
                                                               a_src2, a_dst2, als2, ald2);
  aggregate2<<<12500, 256, 0, stream>>>(h2, als2, ald2, offsets, srcs, b2, out2);

  // pool + MLP
  pool_kernel<<<NB, 128, 0, stream>>>(out2, batch, pooled, cnts);
  mlp_kernel<<<NUM_GRAPHS, 64, 0, stream>>>(pooled, cnts, fc1_w, fc1_b, fc2_w, fc2_b, out);
}